// Round 6
// baseline (77.980 us; speedup 1.0000x reference)
//
#include <hip/hip_runtime.h>
#include <math.h>

#define BROWS 8192
#define F 10
#define TJ 512                  // j-rows staged per round
#define QPITCH 20               // qrow row pitch in f16 (40 B)
#define APITCH (TJ + 8)         // augT row pitch in f16 (520)
#define LOG2E 1.44269504088896340736f

#if __has_builtin(__builtin_amdgcn_exp2f)
#define EXP2F(x) __builtin_amdgcn_exp2f(x)
#else
#define EXP2F(x) exp2f(x)
#endif

typedef _Float16 half4 __attribute__((ext_vector_type(4)));
typedef __fp16 fp16x2 __attribute__((ext_vector_type(2)));
typedef float floatx4 __attribute__((ext_vector_type(4)));

__device__ __forceinline__ half4 exp4_to_h4(float a, float b, float c, float d) {
#if __has_builtin(__builtin_amdgcn_cvt_pkrtz)
    union { fp16x2 h2[2]; half4 h4; } u;
    u.h2[0] = __builtin_amdgcn_cvt_pkrtz(EXP2F(a), EXP2F(b));
    u.h2[1] = __builtin_amdgcn_cvt_pkrtz(EXP2F(c), EXP2F(d));
    return u.h4;
#else
    half4 r;
    r[0] = (_Float16)EXP2F(a); r[1] = (_Float16)EXP2F(b);
    r[2] = (_Float16)EXP2F(c); r[3] = (_Float16)EXP2F(d);
    return r;
#endif
}

__device__ __forceinline__ uint32_t pack2(_Float16 a, _Float16 b) {
    union { _Float16 h[2]; uint32_t u; } x;
    x.h[0] = a; x.h[1] = b;
    return x.u;
}

// ---------------------------------------------------------------------------
// Kernel 1: pooled[b][o] = sum_f (sum_m c[m]*x[b][m][f]) * W[f][o]
// c[m] = 0.125 * (offsum[m] + A[0][m] + A[1][m]),  offsum = {1,1,2}
// 128 blocks x 64 threads -> spread across 128 CUs.
// ---------------------------------------------------------------------------
__global__ void pooled_kernel(const float* __restrict__ x,
                              const float* __restrict__ A,
                              const float* __restrict__ W,
                              float* __restrict__ pooled) {
    int b = blockIdx.x * blockDim.x + threadIdx.x;
    if (b >= BROWS) return;

    float c0 = 0.125f * (1.0f + A[0] + A[3]);
    float c1 = 0.125f * (1.0f + A[1] + A[4]);
    float c2 = 0.125f * (2.0f + A[2] + A[5]);

    const float2* xb = (const float2*)(x + (size_t)b * 3 * F);
    float xv[3 * F];
#pragma unroll
    for (int k = 0; k < 15; ++k) {
        float2 t = xb[k];
        xv[2 * k] = t.x; xv[2 * k + 1] = t.y;
    }

    float y[F];
#pragma unroll
    for (int f = 0; f < F; ++f)
        y[f] = c0 * xv[f] + c1 * xv[F + f] + c2 * xv[2 * F + f];

#pragma unroll
    for (int o = 0; o < F; ++o) {
        float acc = 0.0f;
#pragma unroll
        for (int f = 0; f < F; ++f)
            acc = fmaf(y[f], W[f * F + o], acc);
        pooled[(size_t)b * F + o] = acc;
    }
}

// ---------------------------------------------------------------------------
// Kernel 2: single-pass MFMA flash attention over the batch axis.
// Block (512 thr = 8 waves) owns i-tile = 16 rows. Each round stages TJ=512
// j-rows into LDS (qrow row-major for MFMA1-A, augT f-major for MFMA2-A,
// row10 = ones -> softmax denominator). Wave w computes its 64-j slice:
//   MFMA1 (swapped): D1 = Qtile * P_i  -> S^T tile, C-layout == B-layout
//   exp2 -> f16     -> B operand of MFMA2 directly (zero shuffles)
//   MFMA2: acc += augT-frag * expS    (acc = V^T, feature 10 = l)
// End: LDS reduce over the 8 waves, fused normalize, write out.
// Register prefetch of tile t+1's 5 float2 before compute of tile t.
// ---------------------------------------------------------------------------
__global__ void attn_kernel(const float* __restrict__ pooled,
                            float* __restrict__ out) {
    __shared__ __align__(16) _Float16 qrow[TJ * QPITCH];   // 20480 B
    __shared__ __align__(16) _Float16 augT[16 * APITCH];   // 16640 B
    __shared__ __align__(16) float red[8 * 16 * 12];       //  6144 B

    const int tid  = threadIdx.x;
    const int wave = tid >> 6;
    const int lane = tid & 63;
    const int m    = lane & 15;
    const int quad = lane >> 4;
    const int irow = blockIdx.x * 16 + m;

    // B1 fragment: B[k=f][n=i] = pooled[irow][quad*4+idx] * log2(e)
    half4 b1;
#pragma unroll
    for (int idx = 0; idx < 4; ++idx) {
        int f = quad * 4 + idx;
        float v = (f < F) ? pooled[(size_t)irow * F + f] * LOG2E : 0.0f;
        b1[idx] = (_Float16)v;
    }

    // constant rows of augT: row 10 = ones (l-sum), rows 11..15 = zeros
    for (int e = tid; e < 6 * APITCH; e += 512) {
        int n = 10 + e / APITCH;
        int j = e % APITCH;
        augT[n * APITCH + j] = (n == 10) ? (_Float16)1.0f : (_Float16)0.0f;
    }

    floatx4 acc0 = {0.f, 0.f, 0.f, 0.f};
    floatx4 acc1 = {0.f, 0.f, 0.f, 0.f};

    // prefetch tile 0 (thread t owns j-row t of the tile)
    float2 s0, s1, s2, s3, s4;
    {
        const float2* src = (const float2*)(pooled + (size_t)tid * F);
        s0 = src[0]; s1 = src[1]; s2 = src[2]; s3 = src[3]; s4 = src[4];
    }

    for (int t = 0; t < BROWS / TJ; ++t) {
        __syncthreads();   // previous round's LDS reads complete
        {   // convert + store staged row (j = t*TJ + tid)
            _Float16 h0 = (_Float16)s0.x, h1 = (_Float16)s0.y;
            _Float16 h2 = (_Float16)s1.x, h3 = (_Float16)s1.y;
            _Float16 h4 = (_Float16)s2.x, h5 = (_Float16)s2.y;
            _Float16 h6 = (_Float16)s3.x, h7 = (_Float16)s3.y;
            _Float16 h8 = (_Float16)s4.x, h9 = (_Float16)s4.y;

            uint32_t* qr = (uint32_t*)&qrow[tid * QPITCH];
            qr[0] = pack2(h0, h1); qr[1] = pack2(h2, h3); qr[2] = pack2(h4, h5);
            qr[3] = pack2(h6, h7); qr[4] = pack2(h8, h9);
            qr[5] = 0u; qr[6] = 0u; qr[7] = 0u;   // k=10..15 must be 0-safe

            augT[0 * APITCH + tid] = h0; augT[1 * APITCH + tid] = h1;
            augT[2 * APITCH + tid] = h2; augT[3 * APITCH + tid] = h3;
            augT[4 * APITCH + tid] = h4; augT[5 * APITCH + tid] = h5;
            augT[6 * APITCH + tid] = h6; augT[7 * APITCH + tid] = h7;
            augT[8 * APITCH + tid] = h8; augT[9 * APITCH + tid] = h9;
        }
        __syncthreads();

        // prefetch tile t+1 (lands during MFMA loop below)
        if (t + 1 < BROWS / TJ) {
            const float2* src = (const float2*)(pooled +
                                (size_t)((t + 1) * TJ + tid) * F);
            s0 = src[0]; s1 = src[1]; s2 = src[2]; s3 = src[3]; s4 = src[4];
        }

        // wave w handles j-slice [wave*64, wave*64+64) of the staged tile
#pragma unroll
        for (int c = 0; c < 4; ++c) {
            const int jb = wave * 64 + c * 16;
            half4 a1 = *(const half4*)&qrow[(jb + m) * QPITCH + quad * 4];
            floatx4 d1 = __builtin_amdgcn_mfma_f32_16x16x16f16(
                a1, b1, (floatx4){0.f, 0.f, 0.f, 0.f}, 0, 0, 0);
            half4 a2 = exp4_to_h4(d1[0], d1[1], d1[2], d1[3]);
            half4 ag = *(const half4*)&augT[m * APITCH + jb + quad * 4];
            if (c & 1)
                acc1 = __builtin_amdgcn_mfma_f32_16x16x16f16(ag, a2, acc1, 0, 0, 0);
            else
                acc0 = __builtin_amdgcn_mfma_f32_16x16x16f16(ag, a2, acc0, 0, 0, 0);
        }
    }

    floatx4 acc = acc0 + acc1;   // lane: V^T[f=quad*4+r][i=m], f=10 -> l

    if (quad < 3)
        *(floatx4*)&red[(wave * 16 + m) * 12 + quad * 4] = acc;
    __syncthreads();

    if (tid < 160) {
        const int i16 = tid / 10;
        const int f   = tid % 10;
        float sum = 0.0f, l = 0.0f;
#pragma unroll
        for (int w = 0; w < 8; ++w) {
            sum += red[(w * 16 + i16) * 12 + f];
            l   += red[(w * 16 + i16) * 12 + 10];
        }
        out[(size_t)(blockIdx.x * 16 + i16) * F + f] = sum / l;
    }
}

// ---------------------------------------------------------------------------
extern "C" void kernel_launch(void* const* d_in, const int* in_sizes, int n_in,
                              void* d_out, int out_size, void* d_ws, size_t ws_size,
                              hipStream_t stream) {
    const float* x = (const float*)d_in[0];   // [8192,3,10]
    const float* A = (const float*)d_in[1];   // [3,3]
    const float* W = (const float*)d_in[2];   // [10,10]
    float* out = (float*)d_out;               // [8192,10]
    float* pooled = (float*)d_ws;             // 327680 B

    pooled_kernel<<<BROWS / 64, 64, 0, stream>>>(x, A, W, pooled);
    attn_kernel<<<BROWS / 16, 512, 0, stream>>>(pooled, out);
}

// Round 7
// 76.456 us; speedup vs baseline: 1.0199x; 1.0199x over previous
//
#include <hip/hip_runtime.h>
#include <math.h>

#define BROWS 8192
#define F 10
#define TJ 512                  // j-rows staged per round
#define QP 20                   // poolQ/qbuf row pitch in f16 (40 B)
#define AP 520                  // abuf row pitch in f16 (1040 B)
#define NT (BROWS / TJ)         // 16 tiles
#define LOG2E 1.44269504088896340736f

#if __has_builtin(__builtin_amdgcn_exp2f)
#define EXP2F(x) __builtin_amdgcn_exp2f(x)
#else
#define EXP2F(x) exp2f(x)
#endif

typedef _Float16 half4 __attribute__((ext_vector_type(4)));
typedef __fp16 fp16x2 __attribute__((ext_vector_type(2)));
typedef float floatx4 __attribute__((ext_vector_type(4)));

__device__ __forceinline__ half4 exp4_to_h4(float a, float b, float c, float d) {
#if __has_builtin(__builtin_amdgcn_cvt_pkrtz)
    union { fp16x2 h2[2]; half4 h4; } u;
    u.h2[0] = __builtin_amdgcn_cvt_pkrtz(EXP2F(a), EXP2F(b));
    u.h2[1] = __builtin_amdgcn_cvt_pkrtz(EXP2F(c), EXP2F(d));
    return u.h4;
#else
    half4 r;
    r[0] = (_Float16)EXP2F(a); r[1] = (_Float16)EXP2F(b);
    r[2] = (_Float16)EXP2F(c); r[3] = (_Float16)EXP2F(d);
    return r;
#endif
}

__device__ __forceinline__ uint32_t pack2(_Float16 a, _Float16 b) {
    union { _Float16 h[2]; uint32_t u; } x;
    x.h[0] = a; x.h[1] = b;
    return x.u;
}

// async global->LDS DMA, 16B/lane; lds addr must be (wave-uniform base + lane*16)
// — the R3-verified pattern.
__device__ __forceinline__ void gload_lds16(const void* g, void* l) {
#if __has_builtin(__builtin_amdgcn_global_load_lds)
    __builtin_amdgcn_global_load_lds(
        (const __attribute__((address_space(1))) void*)g,
        (__attribute__((address_space(3))) void*)l, 16, 0, 0);
#else
    *(float4*)l = *(const float4*)g;
#endif
}

// ---------------------------------------------------------------------------
// Kernel 1: pooled in TWO f16 layouts.
//   poolQ[b][0..19]: feats 0..9, 10..19 = 0  (row-major, 40 B rows)
//   poolT[f][b]    : transposed               (for augT row DMA)
// c[m] = 0.125 * (offsum[m] + A[0][m] + A[1][m]), offsum = {1,1,2}
// ---------------------------------------------------------------------------
__global__ void pooled_kernel(const float* __restrict__ x,
                              const float* __restrict__ A,
                              const float* __restrict__ W,
                              _Float16* __restrict__ poolQ,
                              _Float16* __restrict__ poolT) {
    int b = blockIdx.x * blockDim.x + threadIdx.x;
    if (b >= BROWS) return;

    float c0 = 0.125f * (1.0f + A[0] + A[3]);
    float c1 = 0.125f * (1.0f + A[1] + A[4]);
    float c2 = 0.125f * (2.0f + A[2] + A[5]);

    const float2* xb = (const float2*)(x + (size_t)b * 3 * F);
    float xv[3 * F];
#pragma unroll
    for (int k = 0; k < 15; ++k) {
        float2 t = xb[k];
        xv[2 * k] = t.x; xv[2 * k + 1] = t.y;
    }

    float y[F];
#pragma unroll
    for (int f = 0; f < F; ++f)
        y[f] = c0 * xv[f] + c1 * xv[F + f] + c2 * xv[2 * F + f];

    float po[F];
#pragma unroll
    for (int o = 0; o < F; ++o) {
        float acc = 0.0f;
#pragma unroll
        for (int f = 0; f < F; ++f)
            acc = fmaf(y[f], W[f * F + o], acc);
        po[o] = acc;
    }

    // poolQ row: 10 u32 (20 f16), 8-B aligned stores
    uint2* qd = (uint2*)(poolQ + (size_t)b * QP);
    qd[0] = make_uint2(pack2((_Float16)po[0], (_Float16)po[1]),
                       pack2((_Float16)po[2], (_Float16)po[3]));
    qd[1] = make_uint2(pack2((_Float16)po[4], (_Float16)po[5]),
                       pack2((_Float16)po[6], (_Float16)po[7]));
    qd[2] = make_uint2(pack2((_Float16)po[8], (_Float16)po[9]), 0u);
    qd[3] = make_uint2(0u, 0u);
    qd[4] = make_uint2(0u, 0u);

#pragma unroll
    for (int o = 0; o < F; ++o)
        poolT[(size_t)o * BROWS + b] = (_Float16)po[o];   // coalesced over b
}

// ---------------------------------------------------------------------------
// Kernel 2: single-pass MFMA flash attention, DMA-staged, double-buffered,
// ONE barrier per tile. Block (512 thr = 8 waves) owns i-tile = 16 rows.
//   qbuf tile: contiguous 20480 B slab of poolQ   (20 wave-DMAs)
//   abuf rows 0..9: poolT rows, 1024 B each       (10 wave-DMAs)
//   abuf row 10 = ones (softmax denom), 11..15 = 0 (written once, both bufs)
// Wave w computes j-slice [w*64, w*64+64):
//   MFMA1 (swapped): D1 = Qtile * P_i -> S^T, C-layout == B-layout of MFMA2
//   exp2 -> f16 -> MFMA2: acc += abuf-frag * expS   (acc = V^T, row 10 = l)
// End: LDS reduce over 8 waves, fused normalize.
// ---------------------------------------------------------------------------
__global__ void attn_kernel(const _Float16* __restrict__ poolQ,
                            const _Float16* __restrict__ poolT,
                            float* __restrict__ out) {
    __shared__ __align__(16) _Float16 qbuf[2][TJ * QP];   // 2 x 20480 B
    __shared__ __align__(16) _Float16 abuf[2][16 * AP];   // 2 x 16640 B
    __shared__ __align__(16) float red[8 * 16 * 12];      // 6144 B

    const int tid  = threadIdx.x;
    const int wave = tid >> 6;
    const int lane = tid & 63;
    const int m    = lane & 15;
    const int quad = lane >> 4;
    const int irow = blockIdx.x * 16 + m;

    // B1 fragment: B[k=f][n=i] = poolQ[irow][quad*4+idx] * log2(e)
    half4 b1;
#pragma unroll
    for (int idx = 0; idx < 4; ++idx) {
        int f = quad * 4 + idx;
        float v = (f < F) ? (float)poolQ[(size_t)irow * QP + f] * LOG2E : 0.0f;
        b1[idx] = (_Float16)v;
    }

    // constant rows (10..15) of both abuf buffers: row 10 = 1, rest = 0
    for (int e = tid; e < 2 * 6 * AP; e += 512) {
        int bufi = e / (6 * AP);
        int r    = e % (6 * AP);
        int n    = 10 + r / AP;
        int j    = r % AP;
        abuf[bufi][n * AP + j] = (n == 10) ? (_Float16)1.0f : (_Float16)0.0f;
    }

    // DMA one tile into buffer `bufi` (wave-cooperative, 30 DMAs total)
    auto dma_tile = [&](int t, int bufi) {
        const char* qs = (const char*)poolQ + (size_t)t * TJ * QP * 2;  // 20480 B
        char* qd = (char*)&qbuf[bufi][0];
        for (int d = wave; d < 20; d += 8)
            gload_lds16(qs + d * 1024 + lane * 16, qd + d * 1024 + lane * 16);
        char* ad = (char*)&abuf[bufi][0];
        for (int n = wave; n < F; n += 8)
            gload_lds16((const char*)(poolT + (size_t)n * BROWS + t * TJ) + lane * 16,
                        ad + n * (AP * 2) + lane * 16);
    };

    floatx4 acc0 = {0.f, 0.f, 0.f, 0.f};
    floatx4 acc1 = {0.f, 0.f, 0.f, 0.f};

    dma_tile(0, 0);
    __syncthreads();   // drains DMA vmcnt + the const-row LDS writes

    for (int t = 0; t < NT; ++t) {
        const int buf = t & 1;
        if (t + 1 < NT) dma_tile(t + 1, buf ^ 1);   // flies during compute

#pragma unroll
        for (int c = 0; c < 4; ++c) {
            const int jb = wave * 64 + c * 16;
            half4 a1 = *(const half4*)&qbuf[buf][(jb + m) * QP + quad * 4];
            floatx4 d1 = __builtin_amdgcn_mfma_f32_16x16x16f16(
                a1, b1, (floatx4){0.f, 0.f, 0.f, 0.f}, 0, 0, 0);
            half4 a2 = exp4_to_h4(d1[0], d1[1], d1[2], d1[3]);
            half4 ag = *(const half4*)&abuf[buf][m * AP + jb + quad * 4];
            if (c & 1)
                acc1 = __builtin_amdgcn_mfma_f32_16x16x16f16(ag, a2, acc1, 0, 0, 0);
            else
                acc0 = __builtin_amdgcn_mfma_f32_16x16x16f16(ag, a2, acc0, 0, 0, 0);
        }
        __syncthreads();   // one barrier/tile: drains t+1 DMAs, releases buf
    }

    floatx4 acc = acc0 + acc1;   // lane: V^T[f=quad*4+r][i=m], f=10 -> l

    if (quad < 3)
        *(floatx4*)&red[(wave * 16 + m) * 12 + quad * 4] = acc;
    __syncthreads();

    if (tid < 160) {
        const int i16 = tid / 10;
        const int f   = tid % 10;
        float sum = 0.0f, l = 0.0f;
#pragma unroll
        for (int w = 0; w < 8; ++w) {
            sum += red[(w * 16 + i16) * 12 + f];
            l   += red[(w * 16 + i16) * 12 + 10];
        }
        out[(size_t)(blockIdx.x * 16 + i16) * F + f] = sum / l;
    }
}

// ---------------------------------------------------------------------------
extern "C" void kernel_launch(void* const* d_in, const int* in_sizes, int n_in,
                              void* d_out, int out_size, void* d_ws, size_t ws_size,
                              hipStream_t stream) {
    const float* x = (const float*)d_in[0];   // [8192,3,10]
    const float* A = (const float*)d_in[1];   // [3,3]
    const float* W = (const float*)d_in[2];   // [10,10]
    float* out = (float*)d_out;               // [8192,10]

    _Float16* poolQ = (_Float16*)d_ws;                        // 8192*20*2 = 327680 B
    _Float16* poolT = (_Float16*)((char*)d_ws + 327680);      // 10*8192*2 = 163840 B

    pooled_kernel<<<BROWS / 64, 64, 0, stream>>>(x, A, W, poolQ, poolT);
    attn_kernel<<<BROWS / 16, 512, 0, stream>>>(poolQ, poolT, out);
}